// Round 3
// baseline (190.663 us; speedup 1.0000x reference)
//
#include <hip/hip_runtime.h>
#include <math.h>

#define BATCH 16
#define SEQ   2048      // L == T
#define DIM   512
#define NCHUNK 64       // chunks per (tensor, batch); needs ws >= 2*16*64*512*4 = 4 MiB + pad

// ws layout: float partials[2*BATCH*NCHUNK*DIM] at offset 0.

__global__ void __launch_bounds__(128)
max_kernel(const float* __restrict__ x,
           const float* __restrict__ y,
           const int* __restrict__ mask_x,
           const int* __restrict__ mask_y,
           float* __restrict__ partials,
           int nchunk) {
    // grid: 2*BATCH*nchunk blocks, 128 threads (128*float4 = 512 floats = one row)
    int idx = blockIdx.x;
    int chunk = idx % nchunk;
    int b = (idx / nchunk) % BATCH;
    int tensor = idx / (nchunk * BATCH);
    const float* src = (tensor == 0 ? x : y);
    const int* m = (tensor == 0 ? mask_x : mask_y) + (size_t)b * SEQ;
    int t = threadIdx.x;

    // --- compute len = SEQ - sum(mask row) in-block (mask row is L2-hot) ---
    int s = 0;
    #pragma unroll
    for (int i = t; i < SEQ / 4; i += 128) {
        int4 v = reinterpret_cast<const int4*>(m)[i];
        s += v.x + v.y + v.z + v.w;
    }
    #pragma unroll
    for (int off = 32; off > 0; off >>= 1) s += __shfl_down(s, off, 64);
    __shared__ int red[2];
    if ((t & 63) == 0) red[t >> 6] = s;
    __syncthreads();
    int len = SEQ - (red[0] + red[1]);

    // --- dynamic chunking over the VALID prefix only -> balanced blocks ---
    int rows = (len + nchunk - 1) / nchunk;
    int s0 = chunk * rows;
    int s1 = min(s0 + rows, len);
    float4 acc = make_float4(-INFINITY, -INFINITY, -INFINITY, -INFINITY);
    const float* base = src + ((size_t)b * SEQ) * DIM + t * 4;
    for (int sr = s0; sr < s1; ++sr) {
        float4 v = *reinterpret_cast<const float4*>(base + (size_t)sr * DIM);
        acc.x = fmaxf(acc.x, v.x);
        acc.y = fmaxf(acc.y, v.y);
        acc.z = fmaxf(acc.z, v.z);
        acc.w = fmaxf(acc.w, v.w);
    }
    float4* dst = reinterpret_cast<float4*>(
        partials + ((size_t)(tensor * BATCH + b) * nchunk + chunk) * DIM) + t;
    *dst = acc;
}

__global__ void __launch_bounds__(256)
out_kernel(const float* __restrict__ partials,
           const float* __restrict__ W,
           const float* __restrict__ bias,
           float* __restrict__ out,
           int nchunk) {
    int b = blockIdx.x;   // BATCH blocks
    int t = threadIdx.x;  // 256
    float acc = 0.f;
    for (int d2 = t; d2 < 2 * DIM; d2 += 256) {
        int tensor = d2 >> 9;          // /DIM
        int d = d2 & (DIM - 1);        // %DIM
        const float* p = partials + ((size_t)(tensor * BATCH + b) * nchunk) * DIM + d;
        float mx = -INFINITY;
        for (int c = 0; c < nchunk; ++c) mx = fmaxf(mx, p[(size_t)c * DIM]);
        acc += mx * W[d2];
    }
    #pragma unroll
    for (int off = 32; off > 0; off >>= 1) acc += __shfl_down(acc, off, 64);
    __shared__ float red[4];
    if ((t & 63) == 0) red[t >> 6] = acc;
    __syncthreads();
    if (t == 0) out[b] = red[0] + red[1] + red[2] + red[3] + bias[0];
}

extern "C" void kernel_launch(void* const* d_in, const int* in_sizes, int n_in,
                              void* d_out, int out_size, void* d_ws, size_t ws_size,
                              hipStream_t stream) {
    const float* x      = (const float*)d_in[0];
    const float* y      = (const float*)d_in[1];
    const int*   mask_x = (const int*)d_in[2];
    const int*   mask_y = (const int*)d_in[3];
    const float* W      = (const float*)d_in[4];
    const float* bias   = (const float*)d_in[5];
    float* out = (float*)d_out;

    float* partials = (float*)d_ws;

    // choose chunk count based on workspace (deterministic per process)
    int nchunk = (int)(ws_size / (2ull * BATCH * DIM * sizeof(float)));
    if (nchunk > NCHUNK) nchunk = NCHUNK;
    if (nchunk < 1) nchunk = 1;

    max_kernel<<<2 * BATCH * nchunk, 128, 0, stream>>>(x, y, mask_x, mask_y,
                                                       partials, nchunk);
    out_kernel<<<BATCH, 256, 0, stream>>>(partials, W, bias, out, nchunk);
}

// Round 4
// 149.295 us; speedup vs baseline: 1.2771x; 1.2771x over previous
//
#include <hip/hip_runtime.h>
#include <math.h>

#define BATCH 16
#define SEQ   2048      // L == T
#define DIM   512
#define NCHUNK 64       // chunks per (tensor, batch)

// ws layout: unsigned gmax[2*BATCH*DIM] at offset 0 (64 KB), memset to 0.

// Order-preserving float->uint bijection: a <= b  <=>  T(a) <= T(b) (unsigned)
__device__ __forceinline__ unsigned T(float f) {
    unsigned u = __float_as_uint(f);
    return (u & 0x80000000u) ? ~u : (u | 0x80000000u);
}
__device__ __forceinline__ float invT(unsigned v) {
    unsigned u = (v & 0x80000000u) ? (v & 0x7FFFFFFFu) : ~v;
    return __uint_as_float(u);
}

__global__ void __launch_bounds__(128)
maxatomic_kernel(const float* __restrict__ x,
                 const float* __restrict__ y,
                 const int* __restrict__ mask_x,
                 const int* __restrict__ mask_y,
                 unsigned* __restrict__ gmax,
                 int nchunk) {
    // grid: 2*BATCH*nchunk blocks, 128 threads (128*float4 = 512 floats = one row)
    int idx = blockIdx.x;
    int chunk = idx % nchunk;
    int b = (idx / nchunk) % BATCH;
    int tensor = idx / (nchunk * BATCH);
    const float* src = (tensor == 0 ? x : y);
    const int* m = (tensor == 0 ? mask_x : mask_y) + (size_t)b * SEQ;
    int t = threadIdx.x;

    // --- len = SEQ - sum(mask row); mask row is L2-hot across sibling blocks ---
    int s = 0;
    #pragma unroll
    for (int i = t; i < SEQ / 4; i += 128) {
        int4 v = reinterpret_cast<const int4*>(m)[i];
        s += v.x + v.y + v.z + v.w;
    }
    #pragma unroll
    for (int off = 32; off > 0; off >>= 1) s += __shfl_down(s, off, 64);
    __shared__ int red[2];
    if ((t & 63) == 0) red[t >> 6] = s;
    __syncthreads();
    int len = SEQ - (red[0] + red[1]);

    // --- dynamic chunking over the VALID prefix only -> balanced blocks ---
    int rows = (len + nchunk - 1) / nchunk;
    int s0 = chunk * rows;
    int s1 = min(s0 + rows, len);
    float4 acc = make_float4(-INFINITY, -INFINITY, -INFINITY, -INFINITY);
    const float* base = src + ((size_t)b * SEQ) * DIM + t * 4;
    for (int sr = s0; sr < s1; ++sr) {
        float4 v = *reinterpret_cast<const float4*>(base + (size_t)sr * DIM);
        acc.x = fmaxf(acc.x, v.x);
        acc.y = fmaxf(acc.y, v.y);
        acc.z = fmaxf(acc.z, v.z);
        acc.w = fmaxf(acc.w, v.w);
    }

    if (s0 < s1) {  // only chunks that saw data contribute
        unsigned* dst = gmax + ((size_t)(tensor * BATCH + b)) * DIM + t * 4;
        atomicMax(dst + 0, T(acc.x));
        atomicMax(dst + 1, T(acc.y));
        atomicMax(dst + 2, T(acc.z));
        atomicMax(dst + 3, T(acc.w));
    }
}

__global__ void __launch_bounds__(512)
out_kernel(const unsigned* __restrict__ gmax,
           const float* __restrict__ W,
           const float* __restrict__ bias,
           float* __restrict__ out) {
    int b = blockIdx.x;   // BATCH blocks
    int d = threadIdx.x;  // 512 = DIM
    float v0 = invT(gmax[(size_t)b * DIM + d]);                 // x_in[b][d]
    float v1 = invT(gmax[(size_t)(BATCH + b) * DIM + d]);       // y_in[b][d]
    float acc = v0 * W[d] + v1 * W[DIM + d];
    #pragma unroll
    for (int off = 32; off > 0; off >>= 1) acc += __shfl_down(acc, off, 64);
    __shared__ float red[8];
    if ((d & 63) == 0) red[d >> 6] = acc;
    __syncthreads();
    if (d == 0) {
        float tot = 0.f;
        #pragma unroll
        for (int i = 0; i < 8; ++i) tot += red[i];
        out[b] = tot + bias[0];
    }
}

extern "C" void kernel_launch(void* const* d_in, const int* in_sizes, int n_in,
                              void* d_out, int out_size, void* d_ws, size_t ws_size,
                              hipStream_t stream) {
    const float* x      = (const float*)d_in[0];
    const float* y      = (const float*)d_in[1];
    const int*   mask_x = (const int*)d_in[2];
    const int*   mask_y = (const int*)d_in[3];
    const float* W      = (const float*)d_in[4];
    const float* bias   = (const float*)d_in[5];
    float* out = (float*)d_out;

    unsigned* gmax = (unsigned*)d_ws;
    int nchunk = NCHUNK;

    hipMemsetAsync(gmax, 0, 2ull * BATCH * DIM * sizeof(unsigned), stream);
    maxatomic_kernel<<<2 * BATCH * nchunk, 128, 0, stream>>>(x, y, mask_x, mask_y,
                                                             gmax, nchunk);
    out_kernel<<<BATCH, 512, 0, stream>>>(gmax, W, bias, out);
}

// Round 14
// 143.795 us; speedup vs baseline: 1.3259x; 1.0382x over previous
//
#include <hip/hip_runtime.h>
#include <math.h>

#define BATCH 16
#define SEQ   2048      // L == T
#define DIM   512
#define NCHUNK 32       // chunks per (tensor, batch)

// ws layout: unsigned gmax[2*BATCH*DIM] at offset 0 (64 KB), memset to 0.

typedef float floatx4 __attribute__((ext_vector_type(4)));

// Order-preserving float->uint bijection: a <= b  <=>  T(a) <= T(b) (unsigned)
__device__ __forceinline__ unsigned T(float f) {
    unsigned u = __float_as_uint(f);
    return (u & 0x80000000u) ? ~u : (u | 0x80000000u);
}
__device__ __forceinline__ float invT(unsigned v) {
    unsigned u = (v & 0x80000000u) ? (v & 0x7FFFFFFFu) : ~v;
    return __uint_as_float(u);
}

__global__ void __launch_bounds__(256)
maxatomic_kernel(const float* __restrict__ x,
                 const float* __restrict__ y,
                 const int* __restrict__ mask_x,
                 const int* __restrict__ mask_y,
                 unsigned* __restrict__ gmax,
                 int nchunk) {
    // grid: 2*BATCH*nchunk blocks, 256 threads.
    // Two halves of the block stream alternating rows (2 rows = 4 KB / iter);
    // LDS combine at the end so only half the threads issue atomics.
    int idx = blockIdx.x;
    int chunk = idx % nchunk;
    int b = (idx / nchunk) % BATCH;
    int tensor = idx / (nchunk * BATCH);
    const float* src = (tensor == 0 ? x : y);
    const int* m = (tensor == 0 ? mask_x : mask_y) + (size_t)b * SEQ;
    int t = threadIdx.x;
    int h = t >> 7;        // half: 0 or 1
    int l = t & 127;       // lane-in-half; owns dims [4l, 4l+4)

    // --- len = SEQ - sum(mask row); mask row is L2-hot across sibling blocks ---
    int s = 0;
    #pragma unroll
    for (int i = t; i < SEQ / 4; i += 256) {
        int4 v = reinterpret_cast<const int4*>(m)[i];
        s += v.x + v.y + v.z + v.w;
    }
    #pragma unroll
    for (int off = 32; off > 0; off >>= 1) s += __shfl_down(s, off, 64);
    __shared__ int red[4];
    if ((t & 63) == 0) red[t >> 6] = s;
    __syncthreads();
    int len = SEQ - (red[0] + red[1] + red[2] + red[3]);

    // --- dynamic chunking over the VALID prefix only -> balanced blocks ---
    int rows = (len + nchunk - 1) / nchunk;
    int s0 = chunk * rows;
    int s1 = min(s0 + rows, len);

    float acx = -INFINITY, acy = -INFINITY, acz = -INFINITY, acw = -INFINITY;
    const float* base = src + ((size_t)b * SEQ) * DIM + l * 4;
    for (int r = s0 + h; r < s1; r += 2) {
        const floatx4* p = reinterpret_cast<const floatx4*>(base + (size_t)r * DIM);
        floatx4 v = __builtin_nontemporal_load(p);
        acx = fmaxf(acx, v.x);
        acy = fmaxf(acy, v.y);
        acz = fmaxf(acz, v.z);
        acw = fmaxf(acw, v.w);
    }

    // --- combine half 1 into half 0 via LDS, then one atomic set per dim ---
    __shared__ float comb[128][4];
    if (h == 1) {
        comb[l][0] = acx; comb[l][1] = acy; comb[l][2] = acz; comb[l][3] = acw;
    }
    __syncthreads();
    if (h == 0 && s0 < s1) {
        acx = fmaxf(acx, comb[l][0]);
        acy = fmaxf(acy, comb[l][1]);
        acz = fmaxf(acz, comb[l][2]);
        acw = fmaxf(acw, comb[l][3]);
        unsigned* dst = gmax + ((size_t)(tensor * BATCH + b)) * DIM + l * 4;
        atomicMax(dst + 0, T(acx));
        atomicMax(dst + 1, T(acy));
        atomicMax(dst + 2, T(acz));
        atomicMax(dst + 3, T(acw));
    }
}

__global__ void __launch_bounds__(512)
out_kernel(const unsigned* __restrict__ gmax,
           const float* __restrict__ W,
           const float* __restrict__ bias,
           float* __restrict__ out) {
    int b = blockIdx.x;   // BATCH blocks
    int d = threadIdx.x;  // 512 = DIM
    float v0 = invT(gmax[(size_t)b * DIM + d]);                 // x_in[b][d]
    float v1 = invT(gmax[(size_t)(BATCH + b) * DIM + d]);       // y_in[b][d]
    float acc = v0 * W[d] + v1 * W[DIM + d];
    #pragma unroll
    for (int off = 32; off > 0; off >>= 1) acc += __shfl_down(acc, off, 64);
    __shared__ float red[8];
    if ((d & 63) == 0) red[d >> 6] = acc;
    __syncthreads();
    if (d == 0) {
        float tot = 0.f;
        #pragma unroll
        for (int i = 0; i < 8; ++i) tot += red[i];
        out[b] = tot + bias[0];
    }
}

extern "C" void kernel_launch(void* const* d_in, const int* in_sizes, int n_in,
                              void* d_out, int out_size, void* d_ws, size_t ws_size,
                              hipStream_t stream) {
    const float* x      = (const float*)d_in[0];
    const float* y      = (const float*)d_in[1];
    const int*   mask_x = (const int*)d_in[2];
    const int*   mask_y = (const int*)d_in[3];
    const float* W      = (const float*)d_in[4];
    const float* bias   = (const float*)d_in[5];
    float* out = (float*)d_out;

    unsigned* gmax = (unsigned*)d_ws;

    (void)hipMemsetAsync(gmax, 0, 2ull * BATCH * DIM * sizeof(unsigned), stream);
    maxatomic_kernel<<<2 * BATCH * NCHUNK, 256, 0, stream>>>(x, y, mask_x, mask_y,
                                                             gmax, NCHUNK);
    out_kernel<<<BATCH, 512, 0, stream>>>(gmax, W, bias, out);
}